// Round 9
// baseline (168.026 us; speedup 1.0000x reference)
//
#include <hip/hip_runtime.h>

constexpr int kB  = 16;
constexpr int kM  = 512;
constexpr int kS  = 32;
constexpr int kE  = 128;
constexpr int kV  = 32000;
constexpr int kVN = kV - 1;   // nil (zero) row index
constexpr int kMS = 132;      // padded LDS stride for hops mem tile

// -------------------------------------------------------------------------
// Kernel 1: story embeddings (R6-proven). 2 rows per 256-thread block,
// grid = 4096. 8 groups of 32 lanes = (row-in-pair, s-phase); each lane
// gathers float4 for 8 s x 2 tables -> 16 UNCONDITIONAL loads in flight
// (nil row = clamp + zero weight). Structurally latency-bound at ~40 µs:
// 33 MB random-gather footprint thrashes every 4 MiB XCD-L2; both the
// VGPR-return and LDS-DMA paths hit the same MSHR x L3-latency wall (R7).
// enc[s][e] = 1 + (e-63)(s-15)/1024 (exact f32 match of numpy formula).
// Block 0 zeroes the barrier counters (group [0..15] + global [16]).
// -------------------------------------------------------------------------
__global__ __launch_bounds__(256) void embed_stories_kernel(
    const int*   __restrict__ stories,   // [B,M,S]
    const float* __restrict__ st_bias,   // [VN,E]
    const float* __restrict__ out_bias,  // [VN,E]
    const float* __restrict__ mem_bias,  // [M,E]
    float*       __restrict__ memory,    // [B,M,E]
    float*       __restrict__ output,    // [B,M,E]
    unsigned*    __restrict__ bar)       // [17] counters -> zeroed by block 0
{
    __shared__ int sidx[2][kS];
    __shared__ __align__(16) float pm[8][kE];
    __shared__ __align__(16) float po[8][kE];

    const int t    = threadIdx.x;
    const int row0 = blockIdx.x * 2;
    if (t < 64) sidx[t >> 5][t & 31] = stories[row0 * kS + t];
    if (blockIdx.x == 0 && t < 32) bar[t] = 0u;
    __syncthreads();

    const int g    = t >> 5;
    const int lane = t & 31;
    const int p    = g >> 2;       // row of pair
    const int ph   = g & 3;        // s-phase
    const int e0   = lane * 4;
    const float ef0 = (float)(e0 - 63), ef1 = (float)(e0 - 62);
    const float ef2 = (float)(e0 - 61), ef3 = (float)(e0 - 60);

    float4 am = {0.f, 0.f, 0.f, 0.f};
    float4 ao = {0.f, 0.f, 0.f, 0.f};
    #pragma unroll
    for (int j = 0; j < 8; ++j) {
        const int s   = ph * 8 + j;
        const int idx = sidx[p][s];
        const int ci  = idx < kVN ? idx : (kVN - 1);       // clamped row
        const float live = (idx < kVN) ? 1.0f : 0.0f;      // nil -> weight 0
        const float sf = (float)(s - 15) * (1.0f / 1024.0f);
        const float4 vm = *(const float4*)(st_bias  + (size_t)ci * kE + e0);
        const float4 vo = *(const float4*)(out_bias + (size_t)ci * kE + e0);
        const float c0 = fmaf(ef0, sf, 1.0f) * live;
        const float c1 = fmaf(ef1, sf, 1.0f) * live;
        const float c2 = fmaf(ef2, sf, 1.0f) * live;
        const float c3 = fmaf(ef3, sf, 1.0f) * live;
        am.x = fmaf(vm.x, c0, am.x); am.y = fmaf(vm.y, c1, am.y);
        am.z = fmaf(vm.z, c2, am.z); am.w = fmaf(vm.w, c3, am.w);
        ao.x = fmaf(vo.x, c0, ao.x); ao.y = fmaf(vo.y, c1, ao.y);
        ao.z = fmaf(vo.z, c2, ao.z); ao.w = fmaf(vo.w, c3, ao.w);
    }
    *(float4*)&pm[g][e0] = am;
    *(float4*)&po[g][e0] = ao;
    __syncthreads();

    const int pr = t >> 7;
    const int e  = t & 127;
    const int row = row0 + pr;
    const int m   = row & (kM - 1);
    const float sm = pm[pr * 4 + 0][e] + pm[pr * 4 + 1][e] +
                     pm[pr * 4 + 2][e] + pm[pr * 4 + 3][e];
    const float so = po[pr * 4 + 0][e] + po[pr * 4 + 1][e] +
                     po[pr * 4 + 2][e] + po[pr * 4 + 3][e];
    memory[(size_t)row * kE + e] = sm + mem_bias[m * kE + e];
    output[(size_t)row * kE + e] = so;
}

// -------------------------------------------------------------------------
// Fence-free spin barrier (R4/R6-proven). Works for the 4-block b-groups
// and the all-64 barrier. Cross-block data via agent-scope RELAXED atomics
// (no cache-maintenance storms — R3 lesson).
// -------------------------------------------------------------------------
__device__ __forceinline__ void spin_barrier(unsigned* ctr, unsigned target)
{
    __syncthreads();
    if (threadIdx.x == 0) {
        __hip_atomic_fetch_add(ctr, 1u, __ATOMIC_RELEASE, __HIP_MEMORY_SCOPE_AGENT);
        while (__hip_atomic_load(ctr, __ATOMIC_RELAXED, __HIP_MEMORY_SCOPE_AGENT) < target)
            __builtin_amdgcn_s_sleep(2);
    }
    __syncthreads();
}
__device__ __forceinline__ void cstore(float* p, float v) {
    __hip_atomic_store(p, v, __ATOMIC_RELAXED, __HIP_MEMORY_SCOPE_AGENT);
}
__device__ __forceinline__ float cload(const float* p) {
    return __hip_atomic_load(p, __ATOMIC_RELAXED, __HIP_MEMORY_SCOPE_AGENT);
}

// -------------------------------------------------------------------------
// Kernel 2 (REGULAR launch, 64 blocks x 1024 threads): q-embed + 3 hops +
// final matmul (merged). Hops: R6-proven, 1 barrier/hop per 4-block b-group.
// Then qtr==0 publishes relu(q) -> xg; all-64 barrier; each block computes
// 500 v-columns of out = x @ w_final, staging xg through reused LDS.
// R8 bugfix: xs staging loads BOTH halves (2048 floats, 1024 threads), and
// the final-phase barrier is uniform (no divergent __syncthreads).
// -------------------------------------------------------------------------
__global__ __launch_bounds__(1024) void hops_final_kernel(
    const int*   __restrict__ queries,   // [B,S]
    const float* __restrict__ q_bias,    // [VN,E]
    const float* __restrict__ memory,    // [B,M,E]
    const float* __restrict__ output,    // [B,M,E]
    const float* __restrict__ w_int,     // [E,E]
    const float* __restrict__ w_out,     // [E,E]
    const float* __restrict__ w_final,   // [E,V]
    float*       __restrict__ numer,     // [2,B,4,E]
    float*       __restrict__ denom,     // [2,B,4]
    float*       __restrict__ xg,        // [E,B] transposed
    unsigned*    __restrict__ bar,       // [17]: [b] groups, [16] global
    float*       __restrict__ out)       // [B,V]
{
    __shared__ __align__(16) float mem_lds[128 * kMS];  // 67584 B
    __shared__ __align__(16) float out_lds[128 * kE];   // 65536 B
    __shared__ float sc_q[128];
    __shared__ __align__(16) float q_s[kE];
    __shared__ float xb[kE];
    __shared__ __align__(16) float part8[8][kE];
    __shared__ int qidx[kS];

    const int bid = blockIdx.x;
    const int b   = bid >> 2;
    const int qtr = bid & 3;
    const int t   = threadIdx.x;
    unsigned* ctr = bar + b;

    // ---- stage quarter into LDS (coalesced float4) ----
    const float* memb = memory + ((size_t)b * kM + qtr * 128) * kE;
    const float* outb = output + ((size_t)b * kM + qtr * 128) * kE;
    #pragma unroll
    for (int i = 0; i < 4; ++i) {
        const int flat = t + i * 1024;
        const int rr = flat >> 5, ff = (flat & 31) * 4;
        *(float4*)&mem_lds[rr * kMS + ff] = *(const float4*)&memb[(size_t)rr * kE + ff];
        *(float4*)&out_lds[rr * kE  + ff] = *(const float4*)&outb[(size_t)rr * kE + ff];
    }
    if (t < kS) qidx[t] = queries[b * kS + t];
    __syncthreads();

    // ---- q embedding (threads 0..255) ----
    if (t < 256) {
        const int g = t >> 5, lane = t & 31, e0 = lane * 4;
        const float f0 = (float)(e0 - 63) * (1.0f / 1024.0f);
        const float f1 = (float)(e0 - 62) * (1.0f / 1024.0f);
        const float f2 = (float)(e0 - 61) * (1.0f / 1024.0f);
        const float f3 = (float)(e0 - 60) * (1.0f / 1024.0f);
        float4 a = {0.f, 0.f, 0.f, 0.f};
        #pragma unroll
        for (int j = 0; j < 4; ++j) {
            const int s   = g * 4 + j;
            const int idx = qidx[s];
            const int ci  = idx < kVN ? idx : (kVN - 1);
            const float live = (idx < kVN) ? 1.0f : 0.0f;
            const float sf = (float)(s - 15);
            const float4 v = *(const float4*)&q_bias[(size_t)ci * kE + e0];
            a.x = fmaf(v.x, fmaf(f0, sf, 1.f) * live, a.x);
            a.y = fmaf(v.y, fmaf(f1, sf, 1.f) * live, a.y);
            a.z = fmaf(v.z, fmaf(f2, sf, 1.f) * live, a.z);
            a.w = fmaf(v.w, fmaf(f3, sf, 1.f) * live, a.w);
        }
        *(float4*)&part8[g][e0] = a;
    }
    __syncthreads();
    if (t < kE) {
        float s = 0.f;
        #pragma unroll
        for (int g = 0; g < 8; ++g) s += part8[g][t];
        q_s[t] = s;
    }
    __syncthreads();

    const int grp = t >> 7;
    const int e   = t & 127;

    for (int hop = 0; hop < 3; ++hop) {
        // ---- scores for own 128 rows: 8 lanes x 16 e per row ----
        {
            const int rw = t >> 3, sub = t & 7;
            const float4* qv = (const float4*)&q_s[sub * 16];
            const float4* mv = (const float4*)&mem_lds[rw * kMS + sub * 16];
            float d = 0.f;
            #pragma unroll
            for (int i = 0; i < 4; ++i) {
                const float4 m4 = mv[i], q4 = qv[i];
                d = fmaf(m4.x, q4.x, d); d = fmaf(m4.y, q4.y, d);
                d = fmaf(m4.z, q4.z, d); d = fmaf(m4.w, q4.w, d);
            }
            d += __shfl_down(d, 4);
            d += __shfl_down(d, 2);
            d += __shfl_down(d, 1);
            if (sub == 0) sc_q[rw] = __expf(d);   // no max-sub: |s| = O(1)
        }
        __syncthreads();

        // ---- numer partial ----
        {
            float acc = 0.f;
            const float* pp = &sc_q[grp * 16];
            const float* ob = &out_lds[grp * 16 * kE + e];
            #pragma unroll
            for (int j = 0; j < 16; ++j)
                acc = fmaf(pp[j], ob[j * kE], acc);
            part8[grp][e] = acc;
        }
        __syncthreads();

        const int pb = hop & 1;
        float* nq = numer + (((size_t)pb * kB + b) * 4 + qtr) * kE;
        if (t < kE) {
            float s = 0.f;
            #pragma unroll
            for (int g = 0; g < 8; ++g) s += part8[g][t];
            cstore(&nq[t], s);
        } else if (t < 192) {
            const int l = t - 128;
            float s2 = sc_q[l] + sc_q[l + 64];
            #pragma unroll
            for (int off = 32; off; off >>= 1) s2 += __shfl_down(s2, off);
            if (l == 0) cstore(&denom[((size_t)pb * kB + b) * 4 + qtr], s2);
        }

        spin_barrier(ctr, 4u * (hop + 1));

        // ---- combine: xb = q + sum(numer)/sum(denom) ----
        if (t < kE) {
            const float* nn = numer + ((size_t)pb * kB + b) * 4 * kE;
            const float* dd = denom + ((size_t)pb * kB + b) * 4;
            const float ns = cload(&nn[t]) + cload(&nn[kE + t]) +
                             cload(&nn[2 * kE + t]) + cload(&nn[3 * kE + t]);
            const float ds = cload(&dd[0]) + cload(&dd[1]) +
                             cload(&dd[2]) + cload(&dd[3]);
            xb[t] = q_s[t] + ns / ds;
        }
        __syncthreads();

        // ---- q' = xb @ W (redundant, 8 k-groups of 16) ----
        {
            const float* w = (hop == 2) ? w_out : w_int;
            float acc = 0.f;
            #pragma unroll
            for (int j = 0; j < 16; ++j) {
                const int k = grp * 16 + j;
                acc = fmaf(xb[k], w[k * kE + e], acc);
            }
            part8[grp][e] = acc;
        }
        __syncthreads();
        if (t < kE) {
            float s = 0.f;
            #pragma unroll
            for (int g = 0; g < 8; ++g) s += part8[g][t];
            q_s[t] = s;
        }
        __syncthreads();
    }

    // ---- publish x, all-64 barrier ----
    if (qtr == 0 && t < kE) cstore(&xg[t * kB + b], fmaxf(q_s[t], 0.f));
    spin_barrier(bar + 16, 64u);

    // ---- final phase: block owns v-range [bid*500, bid*500+500) ----
    // Reuse LDS: xs = mem_lds (2048 floats), ps = out_lds (8000 floats).
    float* xs = mem_lds;
    float* ps = out_lds;
    xs[t]        = cload(&xg[t]);          // e = 0..63   (R8 fix: both
    xs[t + 1024] = cload(&xg[t + 1024]);   // e = 64..127  halves loaded)
    __syncthreads();

    const int h = t >> 9;        // e-half
    const int c = t & 511;       // column within block's range
    const bool valid = c < 500;
    const int v = bid * 500 + c;
    float acc[kB];
    #pragma unroll
    for (int bb = 0; bb < kB; ++bb) acc[bb] = 0.f;
    if (valid) {
        const int e0 = h * 64;
        #pragma unroll 4
        for (int ei = 0; ei < 64; ++ei) {
            const int ee = e0 + ei;
            const float wv = w_final[(size_t)ee * kV + v];
            const float* xr = xs + ee * kB;
            #pragma unroll
            for (int bb = 0; bb < kB; ++bb) acc[bb] = fmaf(xr[bb], wv, acc[bb]);
        }
        if (h == 1) {
            #pragma unroll
            for (int bb = 0; bb < kB; ++bb) ps[c * kB + bb] = acc[bb];
        }
    }
    __syncthreads();             // uniform barrier (R8 fix)
    if (valid && h == 0) {
        #pragma unroll
        for (int bb = 0; bb < kB; ++bb)
            out[(size_t)bb * kV + v] = acc[bb] + ps[c * kB + bb];
    }
}

// -------------------------------------------------------------------------
extern "C" void kernel_launch(void* const* d_in, const int* in_sizes, int n_in,
                              void* d_out, int out_size, void* d_ws, size_t ws_size,
                              hipStream_t stream)
{
    const int*   queries  = (const int*)  d_in[0];
    const int*   stories  = (const int*)  d_in[1];
    const float* q_bias   = (const float*)d_in[2];
    const float* st_bias  = (const float*)d_in[3];
    const float* mem_bias = (const float*)d_in[4];
    const float* out_bias = (const float*)d_in[5];
    const float* w_int    = (const float*)d_in[6];
    const float* w_out    = (const float*)d_in[7];
    const float* w_final  = (const float*)d_in[8];
    float* out = (float*)d_out;

    // ws layout (floats): memory | output | numer | denom | xg | bar
    float* memory = (float*)d_ws;
    float* output = memory + (size_t)kB * kM * kE;        // 1,048,576
    float* numer  = output + (size_t)kB * kM * kE;        // 1,048,576
    float* denom  = numer  + 2 * kB * 4 * kE;             // 16,384
    float* xg     = denom  + 2 * kB * 4;                  // 128
    unsigned* bar = (unsigned*)(xg + kE * kB);            // 2,048

    embed_stories_kernel<<<dim3((kB * kM) / 2), dim3(256), 0, stream>>>(
        stories, st_bias, out_bias, mem_bias, memory, output, bar);

    hops_final_kernel<<<dim3(64), dim3(1024), 0, stream>>>(
        queries, q_bias, memory, output, w_int, w_out, w_final,
        numer, denom, xg, bar, out);
}

// Round 10
// 160.756 us; speedup vs baseline: 1.0452x; 1.0452x over previous
//
#include <hip/hip_runtime.h>

constexpr int kB  = 16;
constexpr int kM  = 512;
constexpr int kS  = 32;
constexpr int kE  = 128;
constexpr int kV  = 32000;
constexpr int kVN = kV - 1;   // nil (zero) row index
constexpr int kMS = 132;      // padded LDS stride for hops mem tile

// -------------------------------------------------------------------------
// Kernel 1: story embeddings (R6-proven). 2 rows per 256-thread block,
// grid = 4096. 8 groups of 32 lanes = (row-in-pair, s-phase); each lane
// gathers float4 for 8 s x 2 tables -> 16 UNCONDITIONAL loads in flight
// (nil row = clamp + zero weight). Structurally latency-bound at ~40 µs:
// 33 MB random-gather footprint thrashes every 4 MiB XCD-L2; both the
// VGPR-return and LDS-DMA paths hit the same MSHR x latency wall (R7).
// enc[s][e] = 1 + (e-63)(s-15)/1024 (exact f32 match of numpy formula).
// Block 0 zeroes the hops barrier counters.
// -------------------------------------------------------------------------
__global__ __launch_bounds__(256) void embed_stories_kernel(
    const int*   __restrict__ stories,   // [B,M,S]
    const float* __restrict__ st_bias,   // [VN,E]
    const float* __restrict__ out_bias,  // [VN,E]
    const float* __restrict__ mem_bias,  // [M,E]
    float*       __restrict__ memory,    // [B,M,E]
    float*       __restrict__ output,    // [B,M,E]
    unsigned*    __restrict__ bar)       // [B] counters -> zeroed by block 0
{
    __shared__ int sidx[2][kS];
    __shared__ __align__(16) float pm[8][kE];
    __shared__ __align__(16) float po[8][kE];

    const int t    = threadIdx.x;
    const int row0 = blockIdx.x * 2;
    if (t < 64) sidx[t >> 5][t & 31] = stories[row0 * kS + t];
    if (blockIdx.x == 0 && t < kB) bar[t] = 0u;
    __syncthreads();

    const int g    = t >> 5;
    const int lane = t & 31;
    const int p    = g >> 2;       // row of pair
    const int ph   = g & 3;        // s-phase
    const int e0   = lane * 4;
    const float ef0 = (float)(e0 - 63), ef1 = (float)(e0 - 62);
    const float ef2 = (float)(e0 - 61), ef3 = (float)(e0 - 60);

    float4 am = {0.f, 0.f, 0.f, 0.f};
    float4 ao = {0.f, 0.f, 0.f, 0.f};
    #pragma unroll
    for (int j = 0; j < 8; ++j) {
        const int s   = ph * 8 + j;
        const int idx = sidx[p][s];
        const int ci  = idx < kVN ? idx : (kVN - 1);       // clamped row
        const float live = (idx < kVN) ? 1.0f : 0.0f;      // nil -> weight 0
        const float sf = (float)(s - 15) * (1.0f / 1024.0f);
        const float4 vm = *(const float4*)(st_bias  + (size_t)ci * kE + e0);
        const float4 vo = *(const float4*)(out_bias + (size_t)ci * kE + e0);
        const float c0 = fmaf(ef0, sf, 1.0f) * live;
        const float c1 = fmaf(ef1, sf, 1.0f) * live;
        const float c2 = fmaf(ef2, sf, 1.0f) * live;
        const float c3 = fmaf(ef3, sf, 1.0f) * live;
        am.x = fmaf(vm.x, c0, am.x); am.y = fmaf(vm.y, c1, am.y);
        am.z = fmaf(vm.z, c2, am.z); am.w = fmaf(vm.w, c3, am.w);
        ao.x = fmaf(vo.x, c0, ao.x); ao.y = fmaf(vo.y, c1, ao.y);
        ao.z = fmaf(vo.z, c2, ao.z); ao.w = fmaf(vo.w, c3, ao.w);
    }
    *(float4*)&pm[g][e0] = am;
    *(float4*)&po[g][e0] = ao;
    __syncthreads();

    const int pr = t >> 7;
    const int e  = t & 127;
    const int row = row0 + pr;
    const int m   = row & (kM - 1);
    const float sm = pm[pr * 4 + 0][e] + pm[pr * 4 + 1][e] +
                     pm[pr * 4 + 2][e] + pm[pr * 4 + 3][e];
    const float so = po[pr * 4 + 0][e] + po[pr * 4 + 1][e] +
                     po[pr * 4 + 2][e] + po[pr * 4 + 3][e];
    memory[(size_t)row * kE + e] = sm + mem_bias[m * kE + e];
    output[(size_t)row * kE + e] = so;
}

// -------------------------------------------------------------------------
// Fence-free 4-block spin barrier (R4/R6-proven). Cross-block data via
// agent-scope RELAXED atomics (no cache-maintenance storms — R3 lesson).
// -------------------------------------------------------------------------
__device__ __forceinline__ void group_barrier(unsigned* ctr, unsigned target)
{
    __syncthreads();
    if (threadIdx.x == 0) {
        __hip_atomic_fetch_add(ctr, 1u, __ATOMIC_RELEASE, __HIP_MEMORY_SCOPE_AGENT);
        while (__hip_atomic_load(ctr, __ATOMIC_RELAXED, __HIP_MEMORY_SCOPE_AGENT) < target)
            __builtin_amdgcn_s_sleep(2);
    }
    __syncthreads();
}
__device__ __forceinline__ void cstore(float* p, float v) {
    __hip_atomic_store(p, v, __ATOMIC_RELAXED, __HIP_MEMORY_SCOPE_AGENT);
}
__device__ __forceinline__ float cload(const float* p) {
    return __hip_atomic_load(p, __ATOMIC_RELAXED, __HIP_MEMORY_SCOPE_AGENT);
}

// -------------------------------------------------------------------------
// Kernel 2 (REGULAR launch, 64 blocks x 1024 threads): q-embed + 3 hops.
// R10 change: group mapping b = bid&15, qtr = bid>>4 — the 4 blocks of a
// b-group have bids congruent mod 16, hence the SAME bid%8 round-robin XCD:
// barrier counters + numer/denom exchanges stay XCD-local in L2 instead of
// crossing chiplets (was b=bid>>2 -> 4 different XCDs per group).
// -------------------------------------------------------------------------
__global__ __launch_bounds__(1024) void hops_kernel(
    const int*   __restrict__ queries,   // [B,S]
    const float* __restrict__ q_bias,    // [VN,E]
    const float* __restrict__ memory,    // [B,M,E]
    const float* __restrict__ output,    // [B,M,E]
    const float* __restrict__ w_int,     // [E,E]
    const float* __restrict__ w_out,     // [E,E]
    float*       __restrict__ numer,     // [2,B,4,E]
    float*       __restrict__ denom,     // [2,B,4]
    float*       __restrict__ xg,        // [E,B] transposed
    unsigned*    __restrict__ bar)       // [B] counters (zeroed by embed)
{
    __shared__ __align__(16) float mem_lds[128 * kMS];
    __shared__ __align__(16) float out_lds[128 * kE];
    __shared__ float sc_q[128];
    __shared__ __align__(16) float q_s[kE];
    __shared__ float xb[kE];
    __shared__ __align__(16) float part8[8][kE];
    __shared__ int qidx[kS];

    const int bid = blockIdx.x;
    const int b   = bid & 15;      // XCD-colocated groups (R10)
    const int qtr = bid >> 4;
    const int t   = threadIdx.x;
    unsigned* ctr = bar + b;

    const float* memb = memory + ((size_t)b * kM + qtr * 128) * kE;
    const float* outb = output + ((size_t)b * kM + qtr * 128) * kE;
    #pragma unroll
    for (int i = 0; i < 4; ++i) {
        const int flat = t + i * 1024;
        const int rr = flat >> 5, ff = (flat & 31) * 4;
        *(float4*)&mem_lds[rr * kMS + ff] = *(const float4*)&memb[(size_t)rr * kE + ff];
        *(float4*)&out_lds[rr * kE  + ff] = *(const float4*)&outb[(size_t)rr * kE + ff];
    }
    if (t < kS) qidx[t] = queries[b * kS + t];
    __syncthreads();

    if (t < 256) {
        const int g = t >> 5, lane = t & 31, e0 = lane * 4;
        const float f0 = (float)(e0 - 63) * (1.0f / 1024.0f);
        const float f1 = (float)(e0 - 62) * (1.0f / 1024.0f);
        const float f2 = (float)(e0 - 61) * (1.0f / 1024.0f);
        const float f3 = (float)(e0 - 60) * (1.0f / 1024.0f);
        float4 a = {0.f, 0.f, 0.f, 0.f};
        #pragma unroll
        for (int j = 0; j < 4; ++j) {
            const int s   = g * 4 + j;
            const int idx = qidx[s];
            const int ci  = idx < kVN ? idx : (kVN - 1);
            const float live = (idx < kVN) ? 1.0f : 0.0f;
            const float sf = (float)(s - 15);
            const float4 v = *(const float4*)&q_bias[(size_t)ci * kE + e0];
            a.x = fmaf(v.x, fmaf(f0, sf, 1.f) * live, a.x);
            a.y = fmaf(v.y, fmaf(f1, sf, 1.f) * live, a.y);
            a.z = fmaf(v.z, fmaf(f2, sf, 1.f) * live, a.z);
            a.w = fmaf(v.w, fmaf(f3, sf, 1.f) * live, a.w);
        }
        *(float4*)&part8[g][e0] = a;
    }
    __syncthreads();
    if (t < kE) {
        float s = 0.f;
        #pragma unroll
        for (int g = 0; g < 8; ++g) s += part8[g][t];
        q_s[t] = s;
    }
    __syncthreads();

    const int grp = t >> 7;
    const int e   = t & 127;

    for (int hop = 0; hop < 3; ++hop) {
        // ---- scores for own 128 rows: 8 lanes x 16 e per row ----
        {
            const int rw = t >> 3, sub = t & 7;
            const float4* qv = (const float4*)&q_s[sub * 16];
            const float4* mv = (const float4*)&mem_lds[rw * kMS + sub * 16];
            float d = 0.f;
            #pragma unroll
            for (int i = 0; i < 4; ++i) {
                const float4 m4 = mv[i], q4 = qv[i];
                d = fmaf(m4.x, q4.x, d); d = fmaf(m4.y, q4.y, d);
                d = fmaf(m4.z, q4.z, d); d = fmaf(m4.w, q4.w, d);
            }
            d += __shfl_down(d, 4);
            d += __shfl_down(d, 2);
            d += __shfl_down(d, 1);
            if (sub == 0) sc_q[rw] = __expf(d);   // no max-sub: |s| = O(1)
        }
        __syncthreads();

        // ---- numer partial ----
        {
            float acc = 0.f;
            const float* pp = &sc_q[grp * 16];
            const float* ob = &out_lds[grp * 16 * kE + e];
            #pragma unroll
            for (int j = 0; j < 16; ++j)
                acc = fmaf(pp[j], ob[j * kE], acc);
            part8[grp][e] = acc;
        }
        __syncthreads();

        const int pb = hop & 1;
        float* nq = numer + (((size_t)pb * kB + b) * 4 + qtr) * kE;
        if (t < kE) {
            float s = 0.f;
            #pragma unroll
            for (int g = 0; g < 8; ++g) s += part8[g][t];
            cstore(&nq[t], s);
        } else if (t < 192) {
            const int l = t - 128;
            float s2 = sc_q[l] + sc_q[l + 64];
            #pragma unroll
            for (int off = 32; off; off >>= 1) s2 += __shfl_down(s2, off);
            if (l == 0) cstore(&denom[((size_t)pb * kB + b) * 4 + qtr], s2);
        }

        group_barrier(ctr, 4u * (hop + 1));

        // ---- combine: xb = q + sum(numer)/sum(denom) ----
        if (t < kE) {
            const float* nn = numer + ((size_t)pb * kB + b) * 4 * kE;
            const float* dd = denom + ((size_t)pb * kB + b) * 4;
            const float ns = cload(&nn[t]) + cload(&nn[kE + t]) +
                             cload(&nn[2 * kE + t]) + cload(&nn[3 * kE + t]);
            const float ds = cload(&dd[0]) + cload(&dd[1]) +
                             cload(&dd[2]) + cload(&dd[3]);
            xb[t] = q_s[t] + ns / ds;
        }
        __syncthreads();

        // ---- q' = xb @ W (redundant, 8 k-groups of 16) ----
        {
            const float* w = (hop == 2) ? w_out : w_int;
            float acc = 0.f;
            #pragma unroll
            for (int j = 0; j < 16; ++j) {
                const int k = grp * 16 + j;
                acc = fmaf(xb[k], w[k * kE + e], acc);
            }
            part8[grp][e] = acc;
        }
        __syncthreads();
        if (t < kE) {
            float s = 0.f;
            #pragma unroll
            for (int g = 0; g < 8; ++g) s += part8[g][t];
            q_s[t] = s;
        }
        __syncthreads();
    }

    if (qtr == 0 && t < kE) xg[t * kB + b] = fmaxf(q_s[t], 0.f);
}

// -------------------------------------------------------------------------
// Kernel 3: out[b,v] = sum_e relu_x[b,e] * w_final[e,v]. (R6-proven)
// 250 blocks x 256 threads: v = bid*128 + (t&127), e-half = t>>7.
// xg read transposed -> uniform scalar loads; halves combined via LDS.
// -------------------------------------------------------------------------
__global__ __launch_bounds__(256) void final_kernel(
    const float* __restrict__ xg,   // [E,B]
    const float* __restrict__ wf,   // [E,V]
    float*       __restrict__ out)  // [B,V]
{
    __shared__ float ps[128 * kB];
    const int t = threadIdx.x;
    const int v = blockIdx.x * 128 + (t & 127);
    const int h = t >> 7;

    float acc[kB];
    #pragma unroll
    for (int b = 0; b < kB; ++b) acc[b] = 0.f;

    const int e0 = h * 64;
    #pragma unroll 4
    for (int ei = 0; ei < 64; ++ei) {
        const int e = e0 + ei;
        const float wv = wf[(size_t)e * kV + v];
        const float* xr = xg + e * kB;
        #pragma unroll
        for (int b = 0; b < kB; ++b) acc[b] = fmaf(xr[b], wv, acc[b]);
    }
    if (h == 1) {
        #pragma unroll
        for (int b = 0; b < kB; ++b) ps[(t & 127) * kB + b] = acc[b];
    }
    __syncthreads();
    if (h == 0) {
        #pragma unroll
        for (int b = 0; b < kB; ++b)
            out[(size_t)b * kV + v] = acc[b] + ps[(t & 127) * kB + b];
    }
}

// -------------------------------------------------------------------------
extern "C" void kernel_launch(void* const* d_in, const int* in_sizes, int n_in,
                              void* d_out, int out_size, void* d_ws, size_t ws_size,
                              hipStream_t stream)
{
    const int*   queries  = (const int*)  d_in[0];
    const int*   stories  = (const int*)  d_in[1];
    const float* q_bias   = (const float*)d_in[2];
    const float* st_bias  = (const float*)d_in[3];
    const float* mem_bias = (const float*)d_in[4];
    const float* out_bias = (const float*)d_in[5];
    const float* w_int    = (const float*)d_in[6];
    const float* w_out    = (const float*)d_in[7];
    const float* w_final  = (const float*)d_in[8];
    float* out = (float*)d_out;

    // ws layout (floats): memory | output | numer | denom | xg | bar
    float* memory = (float*)d_ws;
    float* output = memory + (size_t)kB * kM * kE;        // 1,048,576
    float* numer  = output + (size_t)kB * kM * kE;        // 1,048,576
    float* denom  = numer  + 2 * kB * 4 * kE;             // 16,384
    float* xg     = denom  + 2 * kB * 4;                  // 128
    unsigned* bar = (unsigned*)(xg + kE * kB);            // 2,048

    embed_stories_kernel<<<dim3((kB * kM) / 2), dim3(256), 0, stream>>>(
        stories, st_bias, out_bias, mem_bias, memory, output, bar);

    hops_kernel<<<dim3(64), dim3(1024), 0, stream>>>(
        queries, q_bias, memory, output, w_int, w_out,
        numer, denom, xg, bar);

    final_kernel<<<dim3(kV / 128), dim3(256), 0, stream>>>(xg, w_final, out);
}